// Round 4
// baseline (111.403 us; speedup 1.0000x reference)
//
#include <hip/hip_runtime.h>
#include <hip/hip_bf16.h>
#include <stdint.h>

#define NB 4
#define NS 4096
#define ND 128
#define KVBLK 64
#define NTILES (NS / KVBLK)

typedef __attribute__((ext_vector_type(8))) short short8;
typedef __attribute__((ext_vector_type(4))) float f32x4;
typedef __attribute__((ext_vector_type(16))) float f32x16;
typedef __attribute__((ext_vector_type(2))) int i32x2;

// log2(e) / sqrt(128): folded into Q so scores come out in exp2 domain.
#define QSCALE 0.12751744f

__device__ __forceinline__ unsigned short f2bfu(float f) {
  __hip_bfloat16 h = __float2bfloat16(f);   // RNE; pairs fuse to v_cvt_pk_bf16_f32
  union { __hip_bfloat16 h; unsigned short u; } c; c.h = h; return c.u;
}
__device__ __forceinline__ uint32_t pack2bf(float lo, float hi) {
  return (uint32_t)f2bfu(lo) | ((uint32_t)f2bfu(hi) << 16);
}

__device__ __forceinline__ void gl_lds16(const void* g, void* l) {
  __builtin_amdgcn_global_load_lds(
      (const __attribute__((address_space(1))) uint32_t*)g,
      (__attribute__((address_space(3))) uint32_t*)l, 16, 0, 0);
}

#define MFMA16(a, b, c) __builtin_amdgcn_mfma_f32_16x16x32_bf16((a), (b), (c), 0, 0, 0)
#define MFMA32(a, b, c) __builtin_amdgcn_mfma_f32_32x32x16_bf16((a), (b), (c), 0, 0, 0)

// half-swap: lo' = {lo.lo, hi.lo-shifted}, hi' = {lo.hi-shifted, hi.hi}
#if __has_builtin(__builtin_amdgcn_permlane32_swap)
#define PLSWAP(lo_, hi_)                                                        \
  { i32x2 r_ = __builtin_amdgcn_permlane32_swap((int)(lo_), (int)(hi_), false,  \
                                                false);                         \
    lo_ = (uint32_t)r_[0]; hi_ = (uint32_t)r_[1]; }
#else
#define PLSWAP(lo_, hi_)                                                        \
  { uint32_t sA_ = hi ? (lo_) : (hi_);                                          \
    uint32_t rA_ = (uint32_t)__shfl_xor((int)sA_, 32, 64);                      \
    uint32_t nl_ = hi ? rA_ : (lo_);                                            \
    uint32_t nh_ = hi ? (hi_) : rA_;                                            \
    lo_ = nl_; hi_ = nh_; }
#endif

// ---------------------------------------------------------------------------
// Preconvert x and W to bf16 (linear row-major) so proj can gl_lds-stage.
// ---------------------------------------------------------------------------
__global__ __launch_bounds__(512) void preconv_kernel(
    const float* __restrict__ x,
    const float* __restrict__ Wq, const float* __restrict__ Wk,
    const float* __restrict__ Wv,
    unsigned short* __restrict__ xb, unsigned short* __restrict__ Wb)
{
  const size_t xg8 = (size_t)NB * NS * ND / 8;   // 262144
  size_t i = (size_t)blockIdx.x * 512 + threadIdx.x;
  const float* src; unsigned short* dst; size_t off;
  if (i < xg8) { src = x; dst = xb; off = i * 8; }
  else {
    size_t j = i - xg8;                          // < 6144
    int which = (int)(j / 2048);
    src = which == 0 ? Wq : which == 1 ? Wk : Wv;
    dst = Wb;
    off = j * 8;                                 // dst offset global
    src = src - (size_t)which * 16384;           // so src+off lands right
  }
  float4 a = *(const float4*)(src + off), b2 = *(const float4*)(src + off + 4);
  short8 o;
  o[0] = (short)f2bfu(a.x);  o[1] = (short)f2bfu(a.y);
  o[2] = (short)f2bfu(a.z);  o[3] = (short)f2bfu(a.w);
  o[4] = (short)f2bfu(b2.x); o[5] = (short)f2bfu(b2.y);
  o[6] = (short)f2bfu(b2.z); o[7] = (short)f2bfu(b2.w);
  *(short8*)(dst + off) = o;
}

// ---------------------------------------------------------------------------
// Projection (bf16 in): T = x @ W^T + b  (blockIdx.z: 0=Q,1=K,2=V)
// ---------------------------------------------------------------------------
__global__ __launch_bounds__(256) void proj_kernel(
    const unsigned short* __restrict__ xb, const unsigned short* __restrict__ Wb,
    const float* __restrict__ bq, const float* __restrict__ bk,
    const float* __restrict__ bv,
    unsigned short* __restrict__ Qo, unsigned short* __restrict__ Ko,
    unsigned short* __restrict__ Vt)
{
  __shared__ unsigned short Xs[64 * 128];    // 16 KB
  __shared__ unsigned short Ws[128 * 128];   // 32 KB (overlaid as Tt for V)

  const int tile = blockIdx.x, b = blockIdx.y, which = blockIdx.z;
  const float* bias = which == 0 ? bq : which == 1 ? bk : bv;
  const int t = threadIdx.x, wave = t >> 6, lane = t & 63;
  const int lr = lane & 15, lg = lane >> 4;

  const char* xsrc = (const char*)(xb + ((size_t)b * NS + (size_t)tile * 64) * ND);
#pragma unroll
  for (int i = wave; i < 16; i += 4) {
    int y = i * 1024 + lane * 16;
    int so = y ^ (((y >> 8) & 7) << 4);
    gl_lds16(xsrc + so, (char*)Xs + y);
  }
  const char* wsrc = (const char*)(Wb + (size_t)which * 16384);
#pragma unroll
  for (int i = wave; i < 32; i += 4) {
    int y = i * 1024 + lane * 16;
    int so = y ^ (((y >> 8) & 7) << 4);
    gl_lds16(wsrc + so, (char*)Ws + y);
  }
  __syncthreads();

  short8 af[4];
#pragma unroll
  for (int kk = 0; kk < 4; ++kk) {
    int row = wave * 16 + lr;
    int ba = (row * 256 + kk * 64 + lg * 16) ^ ((row & 7) << 4);
    af[kk] = *(const short8*)((const char*)Xs + ba);
  }
  f32x4 acc[8] = {};
#pragma unroll
  for (int kk = 0; kk < 4; ++kk) {
#pragma unroll
    for (int nf = 0; nf < 8; ++nf) {
      int n = nf * 16 + lr;
      int ba = (n * 256 + kk * 64 + lg * 16) ^ ((n & 7) << 4);
      short8 bf = *(const short8*)((const char*)Ws + ba);
      acc[nf] = MFMA16(af[kk], bf, acc[nf]);
    }
  }

  if (which < 2) {
    unsigned short* Out = (which == 0) ? Qo : Ko;
    const float sc = (which == 0) ? QSCALE : 1.0f;
#pragma unroll
    for (int nf = 0; nf < 8; ++nf) {
      float bb = bias[nf * 16 + lr];
#pragma unroll
      for (int r = 0; r < 4; ++r) {
        float v = (acc[nf][r] + bb) * sc;
        int row = tile * 64 + wave * 16 + lg * 4 + r;
        Out[((size_t)b * NS + row) * ND + nf * 16 + lr] = f2bfu(v);
      }
    }
  } else {
    __syncthreads();                 // all MFMA reads of Ws done
    unsigned short* Tt = Ws;         // [128][72] overlay (18 KB <= 32 KB)
#pragma unroll
    for (int nf = 0; nf < 8; ++nf) {
      float bb = bias[nf * 16 + lr];
#pragma unroll
      for (int r = 0; r < 4; ++r) {
        int e = nf * 16 + lr;
        int sl = wave * 16 + lg * 4 + r;
        Tt[e * 72 + sl] = f2bfu(acc[nf][r] + bb);
      }
    }
    __syncthreads();
    int e = t >> 1, off = (t & 1) * 32;
    const short8* src = (const short8*)(Tt + e * 72 + off);
    short8* dst = (short8*)(Vt + ((size_t)b * ND + e) * NS + (size_t)tile * 64 + off);
#pragma unroll
    for (int i = 0; i < 4; ++i) dst[i] = src[i];
  }
}

// ---------------------------------------------------------------------------
// Flash attention: 4 waves x 32 q-rows, 32x32x16 MFMA, swapped operands.
// 48 KB LDS: K double-buffered (2x16KB) + V single-buffered (16KB) -> 3
// blocks/CU. b-major XCD grouping keeps each XCD's working set (Q of one
// batch + its KV chunks) under 2 MB, inside the 4 MB per-XCD L2.
// ---------------------------------------------------------------------------
__global__ __launch_bounds__(256, 3) void attn_kernel(
    const unsigned short* __restrict__ Q, const unsigned short* __restrict__ K,
    const unsigned short* __restrict__ Vt, float* __restrict__ OP,
    float* __restrict__ Mp, float* __restrict__ Lp, int nchunk, int ntpc)
{
  __shared__ char smem[49152];   // kb0 | kb1 | vb (16 KB each)

  const int Lid = blockIdx.x;
  const int ngroups = NB * nchunk;
  int g, qt;
  if ((ngroups & 7) == 0) {
    int xcd = Lid & 7, s2 = Lid >> 3;
    qt = s2 & 31;
    g = xcd * (ngroups >> 3) + (s2 >> 5);
  } else { qt = Lid & 31; g = Lid >> 5; }
  const int b = g / nchunk, c = g - b * nchunk;   // b-major: XCD shares Q(b)

  const int t = threadIdx.x, wave = t >> 6, lane = t & 63;
  const int lq = lane & 31, hi = lane >> 5;

  const int qrow = qt * 128 + wave * 32 + lq;
  short8 qf[8];
  const unsigned short* Qb = Q + ((size_t)b * NS + qrow) * ND;
#pragma unroll
  for (int kt = 0; kt < 8; ++kt) qf[kt] = *(const short8*)(Qb + kt * 16 + hi * 8);

  const unsigned short* Kc = K + ((size_t)b * NS + (size_t)c * ntpc * KVBLK) * ND;
  const unsigned short* Vb = Vt + (size_t)b * ND * NS;
  const size_t vcol0 = (size_t)c * ntpc * KVBLK;

  char* kb0 = smem;
  char* kb1 = smem + 16384;
  char* vbuf = smem + 32768;

  auto stageK = [&](char* kdst, int tt) {
    const char* ksrc = (const char*)(Kc + (size_t)tt * KVBLK * ND);
#pragma unroll
    for (int i = wave; i < 16; i += 4) {
      int y = i * 1024 + lane * 16;
      int so = y ^ (((y >> 8) & 7) << 4);
      gl_lds16(ksrc + so, kdst + y);
    }
  };
  auto stageV = [&](int tt) {
    const char* vsrc = (const char*)(Vb + vcol0 + (size_t)tt * KVBLK);
#pragma unroll
    for (int i = wave; i < 16; i += 4) {
      int y = i * 1024 + lane * 16;
      int d = y >> 7;
      int cx = (y & 127) ^ ((d & 7) << 4);
      gl_lds16(vsrc + (size_t)d * (NS * 2) + cx, vbuf + y);
    }
  };

  f32x16 oacc[4] = {};
  float m = -1e30f, l = 0.f;

  stageK(kb0, 0);
  stageV(0);
  __syncthreads();

  for (int tt = 0; tt < ntpc; ++tt) {
    const char* kb = (tt & 1) ? kb1 : kb0;
    if (tt + 1 < ntpc) stageK((tt & 1) ? kb0 : kb1, tt + 1);

    // ---- QK^T (swapped): D[kv][q] ----
    f32x16 s0 = {}, s1 = {};
    __builtin_amdgcn_s_setprio(1);
#pragma unroll
    for (int kt = 0; kt < 8; ++kt) {
      int co = (kt * 32 + hi * 16) ^ ((lq & 7) << 4);
      short8 k0 = *(const short8*)(kb + lq * 256 + co);
      short8 k1 = *(const short8*)(kb + (32 + lq) * 256 + co);
      s0 = MFMA32(k0, qf[kt], s0);
      s1 = MFMA32(k1, qf[kt], s1);
    }
    __builtin_amdgcn_s_setprio(0);

    // ---- lane-local online softmax with defer-max (THR=8) ----
    float x0 = fmaxf(s0[0], s1[0]), x1 = fmaxf(s0[1], s1[1]);
    float x2 = fmaxf(s0[2], s1[2]), x3 = fmaxf(s0[3], s1[3]);
#pragma unroll
    for (int r = 4; r < 16; r += 4) {
      x0 = fmaxf(x0, fmaxf(s0[r], s1[r]));
      x1 = fmaxf(x1, fmaxf(s0[r + 1], s1[r + 1]));
      x2 = fmaxf(x2, fmaxf(s0[r + 2], s1[r + 2]));
      x3 = fmaxf(x3, fmaxf(s0[r + 3], s1[r + 3]));
    }
    float px = fmaxf(fmaxf(x0, x1), fmaxf(x2, x3));
    px = fmaxf(px, __shfl_xor(px, 32, 64));      // sync m across lane pair
    if (__any(px > m + 8.f)) {
      float mn = fmaxf(m, px);
      float corr = exp2f(m - mn);
      m = mn;
      l *= corr;
#pragma unroll
      for (int dt = 0; dt < 4; ++dt)
#pragma unroll
        for (int r = 0; r < 16; ++r) oacc[dt][r] *= corr;
    }

    float p0[16], p1[16];
    float u0 = 0.f, u1 = 0.f, u2 = 0.f, u3 = 0.f;
#pragma unroll
    for (int r = 0; r < 16; r += 4) {
      p0[r] = exp2f(s0[r] - m);     p1[r] = exp2f(s1[r] - m);
      p0[r+1] = exp2f(s0[r+1] - m); p1[r+1] = exp2f(s1[r+1] - m);
      p0[r+2] = exp2f(s0[r+2] - m); p1[r+2] = exp2f(s1[r+2] - m);
      p0[r+3] = exp2f(s0[r+3] - m); p1[r+3] = exp2f(s1[r+3] - m);
      u0 += p0[r] + p1[r];       u1 += p0[r+1] + p1[r+1];
      u2 += p0[r+2] + p1[r+2];   u3 += p0[r+3] + p1[r+3];
    }
    l += (u0 + u1) + (u2 + u3);   // lane-half partial; paired in epilogue

    // ---- pack P -> bf16 pairs; permlane half-exchange; PV B-frags ----
    uint32_t pk0[8], pk1[8];
#pragma unroll
    for (int i = 0; i < 8; ++i) {
      pk0[i] = pack2bf(p0[2 * i], p0[2 * i + 1]);
      pk1[i] = pack2bf(p1[2 * i], p1[2 * i + 1]);
    }
    short8 pfrag[4];
#pragma unroll
    for (int mt = 0; mt < 2; ++mt) {
      const uint32_t* pk = mt ? pk1 : pk0;
#pragma unroll
      for (int kt2 = 0; kt2 < 2; ++kt2) {
        uint32_t e0 = pk[4 * kt2 + 0], e1 = pk[4 * kt2 + 1];
        uint32_t e2 = pk[4 * kt2 + 2], e3 = pk[4 * kt2 + 3];
        PLSWAP(e0, e2);
        PLSWAP(e1, e3);
        union { uint32_t u[4]; short8 s; } pf;
        pf.u[0] = e0; pf.u[1] = e1; pf.u[2] = e2; pf.u[3] = e3;
        pfrag[mt * 2 + kt2] = pf.s;
      }
    }

    __syncthreads();   // A: V(tt) staged (prev iter) drained + visible

    // ---- PV (swapped): oacc[dt] += V^T[dt] . P^T -> D[d][q] ----
    __builtin_amdgcn_s_setprio(1);
#pragma unroll
    for (int dt = 0; dt < 4; ++dt) {
      int rowb = (dt * 32 + lq) * 128;
      int sw = (lq & 7) << 4;
#pragma unroll
      for (int mt = 0; mt < 2; ++mt)
#pragma unroll
        for (int kt2 = 0; kt2 < 2; ++kt2) {
          int co = (mt * 64 + kt2 * 32 + hi * 16) ^ sw;
          short8 vf = *(const short8*)(vbuf + rowb + co);
          oacc[dt] = MFMA32(vf, pfrag[mt * 2 + kt2], oacc[dt]);
        }
    }
    __builtin_amdgcn_s_setprio(0);

    __syncthreads();   // B: all PV reads of vbuf done -> safe to restage
    if (tt + 1 < ntpc) stageV(tt + 1);
  }

  // ---- epilogue: pair-sum l; write unnormalized O^T partial + m,l ----
  float lt = l + __shfl_xor(l, 32, 64);
  const size_t qg = (size_t)qrow;
  float* OPb = OP + ((size_t)(c * NB + b) * ND) * NS + qg;
#pragma unroll
  for (int dt = 0; dt < 4; ++dt)
#pragma unroll
    for (int r = 0; r < 16; ++r) {
      int d = dt * 32 + (r & 3) + 8 * (r >> 2) + 4 * hi;
      OPb[(size_t)d * NS] = oacc[dt][r];
    }
  if (hi == 0) {
    Mp[(size_t)(c * NB + b) * NS + qg] = m;
    Lp[(size_t)(c * NB + b) * NS + qg] = lt;
  }
}

// ---------------------------------------------------------------------------
// Combine partials across chunks + transpose back to [b][q][d].
// ---------------------------------------------------------------------------
__global__ __launch_bounds__(256) void combine_kernel(
    const float* __restrict__ OP, const float* __restrict__ Mp,
    const float* __restrict__ Lp, float* __restrict__ Out, int nchunk)
{
  __shared__ float wn[8][64];
  __shared__ float LT[64][129];

  const int qtile = blockIdx.x, b = blockIdx.y;
  const int t = threadIdx.x;

  if (t < 64) {
    size_t qg = (size_t)qtile * 64 + t;
    float wloc[8];
    float mx = -1e30f;
    for (int cc = 0; cc < nchunk; ++cc)
      mx = fmaxf(mx, Mp[(size_t)(cc * NB + b) * NS + qg]);
    float Lt = 0.f;
    for (int cc = 0; cc < nchunk; ++cc) {
      float w = exp2f(Mp[(size_t)(cc * NB + b) * NS + qg] - mx);
      Lt += w * Lp[(size_t)(cc * NB + b) * NS + qg];
      wloc[cc] = w;
    }
    float inv = 1.0f / Lt;
    for (int cc = 0; cc < nchunk; ++cc) wn[cc][t] = wloc[cc] * inv;
  }
  __syncthreads();

  const int q = t & 63, dl = t >> 6;
#pragma unroll 4
  for (int pass = 0; pass < 32; ++pass) {
    int d = pass * 4 + dl;
    float a = 0.f;
    for (int cc = 0; cc < nchunk; ++cc)
      a += wn[cc][q] *
           OP[((size_t)(cc * NB + b) * ND + d) * NS + (size_t)qtile * 64 + q];
    LT[q][d] = a;
  }
  __syncthreads();

  const int d2 = t & 127, qh = t >> 7;
  float* Ob = Out + ((size_t)b * NS + (size_t)qtile * 64) * ND;
#pragma unroll 4
  for (int pass = 0; pass < 32; ++pass) {
    int qq = pass * 2 + qh;
    Ob[(size_t)qq * ND + d2] = LT[qq][d2];
  }
}

extern "C" void kernel_launch(void* const* d_in, const int* in_sizes, int n_in,
                              void* d_out, int out_size, void* d_ws, size_t ws_size,
                              hipStream_t stream) {
  const float* x  = (const float*)d_in[0];
  const float* Wq = (const float*)d_in[1];
  const float* bq = (const float*)d_in[2];
  const float* Wk = (const float*)d_in[3];
  const float* bk = (const float*)d_in[4];
  const float* Wv = (const float*)d_in[5];
  const float* bv = (const float*)d_in[6];

  const size_t elems = (size_t)NB * NS * ND;
  char* base = (char*)d_ws;
  unsigned short* Qw  = (unsigned short*)base;
  unsigned short* Kw  = Qw + elems;
  unsigned short* Vtw = Kw + elems;
  char* region2 = base + 3 * elems * 2;            // 12 MB offset

  // split-KV factor: largest of {8,4,2,1} fitting ws.
  int nchunk = 8;
  while (nchunk > 1) {
    size_t need = 3 * elems * 2 +
                  (size_t)nchunk * (elems * 4 + 2 * (size_t)NB * NS * 4);
    if (need <= ws_size) break;
    nchunk >>= 1;
  }

  // xb16/Wb16 alias the OP region (proj finishes before attn writes OP).
  unsigned short* xb16 = (unsigned short*)region2;
  unsigned short* Wb16 = xb16 + elems;
  float* OPw = (float*)region2;
  float* Mpw = (float*)(region2 + (size_t)nchunk * elems * 4);
  float* Lpw = Mpw + (size_t)nchunk * NB * NS;

  preconv_kernel<<<dim3(524), 512, 0, stream>>>(x, Wq, Wk, Wv, xb16, Wb16);

  proj_kernel<<<dim3(NS / 64, NB, 3), 256, 0, stream>>>(
      xb16, Wb16, bq, bk, bv, Qw, Kw, Vtw);

  attn_kernel<<<dim3(32 * NB * nchunk), 256, 0, stream>>>(
      Qw, Kw, Vtw, OPw, Mpw, Lpw, nchunk, NTILES / nchunk);

  combine_kernel<<<dim3(NS / 64, NB), 256, 0, stream>>>(
      OPw, Mpw, Lpw, (float*)d_out, nchunk);
}